// Round 3
// baseline (170.565 us; speedup 1.0000x reference)
//
#include <hip/hip_runtime.h>
#include <hip/hip_cooperative_groups.h>

namespace cg = cooperative_groups;

static constexpr int    N      = 2048;
static constexpr int    NBLK   = 256;
static constexpr int    NTHR   = 1024;
static constexpr int    RPB    = 8;     // rows per block (band)
static constexpr double D_MASS = 0.9;
static constexpr double D_TOL  = 0.01;
static constexpr int    NITER  = 50;

struct Ws {
    double a_sum, b_sum;
    double errParts[NBLK];
    double dotParts[NBLK];
    double rowSum0[N];
    float  U[N], V[N], Up[N], Vp[N], row_prev[N], col_prev[N];
    float  partialT[NBLK * N];   // 2 MB column partials, [block][col]
};

// all-threads block reduction; every thread returns the (order-fixed) sum
__device__ __forceinline__ double block_reduce(double v, double* s16) {
    for (int off = 32; off; off >>= 1) v += __shfl_xor(v, off, 64);
    const int wave = threadIdx.x >> 6, lane = threadIdx.x & 63;
    __syncthreads();                  // protect s16 reuse
    if (lane == 0) s16[wave] = v;
    __syncthreads();
    double s = 0.0;
    #pragma unroll
    for (int w = 0; w < 16; ++w) s += s16[w];
    return s;
}

__device__ __forceinline__ void row_scale(Ws* ws, const float* a, double a_sum,
                                          double W, int i, double s) {
    const double Uq     = (double)ws->U[i] / (double)ws->row_prev[i];
    const double rowsum = Uq * W * s;
    const double an     = (double)a[i] / a_sum;
    double r = an / rowsum;
    if (r > 1.0) r = 1.0;
    ws->U[i]        = (float)(Uq * r);
    ws->row_prev[i] = (float)r;
}

__global__ void __launch_bounds__(NTHR, 1)
epot_kernel(const float* __restrict__ C, const float* __restrict__ a,
            const float* __restrict__ b, float* __restrict__ K,
            Ws* __restrict__ ws) {
    cg::grid_group grid = cg::this_grid();
    __shared__ double s16[16];
    __shared__ double sred[128][8];
    __shared__ double sdot[8];

    const int tid  = threadIdx.x;
    const int bid  = blockIdx.x;
    const int lane = tid & 63;
    const int r0   = bid * RPB;
    const int rloc = tid >> 7;        // 0..7: row within band (128 thr/row)
    const int cgrp = tid & 127;       // 0..127: column group within row

    // ---- phase 0: row sums of K0 = exp(-10C) (K0 NOT stored), a/b sums ----
    {
        const int i = r0 + rloc;
        const float4* c4 = (const float4*)(C + (size_t)i * N);
        double s = 0.0;
        #pragma unroll 4
        for (int j4 = cgrp; j4 < N / 4; j4 += 128) {
            float4 c = c4[j4];
            s += (double)expf(-10.0f * c.x) + (double)expf(-10.0f * c.y)
               + (double)expf(-10.0f * c.z) + (double)expf(-10.0f * c.w);
        }
        for (int off = 32; off; off >>= 1) s += __shfl_xor(s, off, 64);
        if (lane == 0) s16[tid >> 6] = s;   // 2 waves per row
        __syncthreads();
        if (tid < RPB) ws->rowSum0[r0 + tid] = s16[2 * tid] + s16[2 * tid + 1];
        if (bid == 0) {
            double t = block_reduce((double)a[tid] + (double)a[tid + 1024], s16);
            if (tid == 0) ws->a_sum = t;
        } else if (bid == 1) {
            double t = block_reduce((double)b[tid] + (double)b[tid + 1024], s16);
            if (tid == 0) ws->b_sum = t;
        }
        const int g = bid * NTHR + tid;
        if (g < N) {
            ws->U[g] = 1.0f; ws->V[g] = 1.0f;
            ws->row_prev[g] = 1.0f; ws->col_prev[g] = 1.0f;
        }
    }
    grid.sync();

    const double k0sum = block_reduce(ws->rowSum0[tid] + ws->rowSum0[tid + 1024], s16);
    const double a_sum = ws->a_sum, b_sum = ws->b_sum;

    // state: K_t = U[i] * K0[i,j] * V[j] * W ; q1=1/row_prev q2=1/col_prev q3=1/scale_prev
    double W = D_MASS / k0sum, scale_prev = 1.0, Wp = 0.0;
    bool done = false;

    for (int cpt = 0; cpt < NITER && !done; ++cpt) {
        const bool erriter = (cpt % 10) == 0;

        if (cpt > 0) {   // lazily apply previous iteration's mass scaling
            double dv = (tid < NBLK) ? ws->dotParts[tid] : 0.0;
            const double sd = block_reduce(dv, s16);
            const double Wq = W / scale_prev;
            scale_prev = D_MASS / (Wq * sd);
            W = D_MASS / sd;
        }
        if (erriter) {
            Wp = W;
            if (tid < RPB) ws->Up[r0 + tid] = ws->U[r0 + tid];
        }
        __syncthreads();

        // ---- A1: row sums + row scaling (iter 0 uses precomputed sums) ----
        if (cpt == 0) {
            if (tid < RPB) row_scale(ws, a, a_sum, W, r0 + tid, ws->rowSum0[r0 + tid]);
        } else {
            const int i = r0 + rloc;
            const float4* c4 = (const float4*)(C + (size_t)i * N);
            const float4* v4 = (const float4*)ws->V;
            double s = 0.0;
            #pragma unroll 4
            for (int j4 = cgrp; j4 < N / 4; j4 += 128) {
                float4 c = c4[j4], vv = v4[j4];
                s += (double)expf(-10.0f * c.x) * vv.x
                   + (double)expf(-10.0f * c.y) * vv.y
                   + (double)expf(-10.0f * c.z) * vv.z
                   + (double)expf(-10.0f * c.w) * vv.w;
            }
            for (int off = 32; off; off >>= 1) s += __shfl_xor(s, off, 64);
            if (lane == 0) s16[tid >> 6] = s;
            __syncthreads();
            if (tid < RPB)
                row_scale(ws, a, a_sum, W, r0 + tid, s16[2 * tid] + s16[2 * tid + 1]);
        }
        __syncthreads();

        // ---- A2: band's column partials (exp recomputed from C), new U ----
        {
            double ub[RPB];
            #pragma unroll
            for (int r = 0; r < RPB; ++r) ub[r] = (double)ws->U[r0 + r];
            const int j0 = 2 * tid;
            double ax = 0.0, ay = 0.0;
            #pragma unroll
            for (int r = 0; r < RPB; ++r) {
                const float2 cv = *(const float2*)(C + (size_t)(r0 + r) * N + j0);
                ax += (double)expf(-10.0f * cv.x) * ub[r];
                ay += (double)expf(-10.0f * cv.y) * ub[r];
            }
            float2 o; o.x = (float)ax; o.y = (float)ay;
            *(float2*)(ws->partialT + (size_t)bid * N + j0) = o;
        }
        grid.sync();

        // ---- B: every block reduces its own 8 columns, col scale, dot ----
        {
            const int g  = tid >> 3;          // 0..127
            const int jj = tid & 7;
            const int j  = bid * RPB + jj;
            sred[g][jj] = (double)ws->partialT[(size_t)g * N + j]
                        + (double)ws->partialT[(size_t)(g + 128) * N + j];
            __syncthreads();
            for (int s2 = 64; s2 > 0; s2 >>= 1) {
                if (g < s2) sred[g][jj] += sred[g + s2][jj];
                __syncthreads();
            }
            if (tid < RPB) {
                const int jc = bid * RPB + tid;
                const double Tj = sred[0][tid];
                const double Vq = (double)ws->V[jc] / (double)ws->col_prev[jc];
                const double colsum = Vq * W * Tj;
                const double bn = (double)b[jc] / b_sum;
                double cf = bn / colsum;
                if (cf > 1.0) cf = 1.0;
                if (erriter) ws->Vp[jc] = ws->V[jc];
                const double Vn = Vq * cf;
                ws->V[jc]        = (float)Vn;
                ws->col_prev[jc] = (float)cf;
                sdot[tid] = Tj * Vn;
            }
            __syncthreads();
            if (tid == 0) {
                double d = 0.0;
                #pragma unroll
                for (int q = 0; q < RPB; ++q) d += sdot[q];
                ws->dotParts[bid] = d;
            }
        }
        grid.sync();

        // ---- err check (every 10 iters), FUSED with speculative output ----
        if (erriter) {
            double dv = (tid < NBLK) ? ws->dotParts[tid] : 0.0;
            const double sd = block_reduce(dv, s16);
            const double Wn = D_MASS / sd;
            const int i = r0 + rloc;
            const double upw = (double)ws->Up[i] * Wp;
            const double unw = (double)ws->U[i] * Wn;
            const float4* c4  = (const float4*)(C + (size_t)i * N);
            float4*       k4  = (float4*)(K + (size_t)i * N);
            const float4* vp4 = (const float4*)ws->Vp;
            const float4* vn4 = (const float4*)ws->V;
            double e2 = 0.0;
            #pragma unroll 4
            for (int j4 = cgrp; j4 < N / 4; j4 += 128) {
                float4 c = c4[j4], vp = vp4[j4], vn = vn4[j4];
                const double k0x = (double)expf(-10.0f * c.x);
                const double k0y = (double)expf(-10.0f * c.y);
                const double k0z = (double)expf(-10.0f * c.z);
                const double k0w = (double)expf(-10.0f * c.w);
                float4 kn;
                kn.x = (float)(unw * k0x * (double)vn.x);
                kn.y = (float)(unw * k0y * (double)vn.y);
                kn.z = (float)(unw * k0z * (double)vn.z);
                kn.w = (float)(unw * k0w * (double)vn.w);
                k4[j4] = kn;                      // speculative final output (Kn)
                double d;
                d = k0x * (upw * (double)vp.x - unw * (double)vn.x); e2 += d * d;
                d = k0y * (upw * (double)vp.y - unw * (double)vn.y); e2 += d * d;
                d = k0z * (upw * (double)vp.z - unw * (double)vn.z); e2 += d * d;
                d = k0w * (upw * (double)vp.w - unw * (double)vn.w); e2 += d * d;
            }
            const double be = block_reduce(e2, s16);
            if (tid == 0) ws->errParts[bid] = be;
            grid.sync();
            double ev = (tid < NBLK) ? ws->errParts[tid] : 0.0;
            const double te = block_reduce(ev, s16);
            done = (sqrt(te) <= D_TOL);   // bitwise-identical in every block
        }
    }

    // ---- only if never converged within 50 iters: final write ----
    if (!done) {
        double dv = (tid < NBLK) ? ws->dotParts[tid] : 0.0;
        const double sd = block_reduce(dv, s16);
        const double Wf = D_MASS / sd;
        const int i = r0 + rloc;
        const double uf = (double)ws->U[i] * Wf;
        const float4* c4 = (const float4*)(C + (size_t)i * N);
        float4*       k4 = (float4*)(K + (size_t)i * N);
        const float4* v4 = (const float4*)ws->V;
        #pragma unroll 4
        for (int j4 = cgrp; j4 < N / 4; j4 += 128) {
            float4 c = c4[j4], vv = v4[j4];
            float4 o;
            o.x = (float)(uf * (double)expf(-10.0f * c.x) * (double)vv.x);
            o.y = (float)(uf * (double)expf(-10.0f * c.y) * (double)vv.y);
            o.z = (float)(uf * (double)expf(-10.0f * c.z) * (double)vv.z);
            o.w = (float)(uf * (double)expf(-10.0f * c.w) * (double)vv.w);
            k4[j4] = o;
        }
    }
}

extern "C" void kernel_launch(void* const* d_in, const int* in_sizes, int n_in,
                              void* d_out, int out_size, void* d_ws, size_t ws_size,
                              hipStream_t stream) {
    const float* C = (const float*)d_in[0];
    const float* a = (const float*)d_in[1];
    const float* b = (const float*)d_in[2];
    float* K = (float*)d_out;
    Ws*    w = (Ws*)d_ws;
    void* args[5] = { (void*)&C, (void*)&a, (void*)&b, (void*)&K, (void*)&w };
    hipLaunchCooperativeKernel((const void*)epot_kernel, dim3(NBLK), dim3(NTHR),
                               args, 0, stream);
}

// Round 5
// 105.431 us; speedup vs baseline: 1.6178x; 1.6178x over previous
//
#include <hip/hip_runtime.h>

static constexpr int    N      = 2048;
static constexpr int    NBLK   = 256;
static constexpr int    NTHR   = 1024;
static constexpr int    RPB    = 8;     // rows per block
static constexpr double D_MASS = 0.9;
static constexpr double D_TOL  = 0.01;
static constexpr int    NITER  = 50;

typedef _Float16 half4_t __attribute__((ext_vector_type(4)));
typedef _Float16 half2_t __attribute__((ext_vector_type(2)));

struct Ws {
    unsigned cnt0, cntP, cntV, cntE;      // flag counters (zeroed per call)
    double bandSum[NBLK];
    double dotParts[NBLK];
    double errParts[NBLK];
    float  V[N];
    float  Vp[N];
    float  partialT[NBLK * N];            // 2 MB column partials
};

__global__ void init_counters(Ws* ws) {
    if (threadIdx.x == 0) { ws->cnt0 = 0u; ws->cntP = 0u; ws->cntV = 0u; ws->cntE = 0u; }
}

// deterministic all-thread block reduction (1024 threads, 16 waves)
__device__ __forceinline__ double block_reduce(double v, double* s16) {
    for (int off = 32; off; off >>= 1) v += __shfl_xor(v, off, 64);
    const int wave = threadIdx.x >> 6, lane = threadIdx.x & 63;
    __syncthreads();                 // protect s16 reuse
    if (lane == 0) s16[wave] = v;
    __syncthreads();
    double s = 0.0;
    #pragma unroll
    for (int w = 0; w < 16; ++w) s += s16[w];
    return s;
}

// single-hop exchange: block-wide arrive (release), spin-wait (acquire)
__device__ __forceinline__ void arrive(unsigned* cnt) {
    __syncthreads();   // all block stores drained before the release add
    if (threadIdx.x == 0)
        __hip_atomic_fetch_add(cnt, 1u, __ATOMIC_RELEASE, __HIP_MEMORY_SCOPE_AGENT);
}
__device__ __forceinline__ void wait_cnt(unsigned* cnt, unsigned target) {
    if (threadIdx.x == 0) {
        while (__hip_atomic_load(cnt, __ATOMIC_RELAXED, __HIP_MEMORY_SCOPE_AGENT) < target)
            __builtin_amdgcn_s_sleep(2);
        __builtin_amdgcn_fence(__ATOMIC_ACQUIRE, "agent");
    }
    __syncthreads();
}

__global__ void __launch_bounds__(NTHR, 1)
epot_kernel(const float* __restrict__ C, const float* __restrict__ a,
            const float* __restrict__ b, float* __restrict__ K,
            Ws* __restrict__ ws)
{
    __shared__ _Float16 band[RPB][N];        // 32 KB: this block's K0 band (fp16)
    __shared__ double s16[16];
    __shared__ double sred[128][8];          // 8 KB column-reduce scratch
    __shared__ double sU[RPB], sUp[RPB], sRowPrev[RPB], sRowSum[RPB];
    __shared__ double sVown[RPB], sColPrev[RPB], sAn[RPB], sBn[RPB], sdotLoc[RPB];

    const int tid  = threadIdx.x;
    const int bid  = blockIdx.x;
    const int lane = tid & 63;
    const int r0   = bid * RPB;
    const int rloc = tid >> 7;               // 0..7 row in band (128 thr/row)
    const int cgrp = tid & 127;              // col group within row

    // ---- phase 0: a/b sums (redundant per block), band = fp16(exp(-10C)) ----
    const double a_sum = block_reduce((double)a[tid] + (double)a[tid + 1024], s16);
    const double b_sum = block_reduce((double)b[tid] + (double)b[tid + 1024], s16);

    {
        const int i = r0 + rloc;
        const float4* c4 = (const float4*)(C + (size_t)i * N);
        double s = 0.0;
        #pragma unroll 4
        for (int j4 = cgrp; j4 < N / 4; j4 += 128) {
            float4 c = c4[j4];
            half4_t h;
            h[0] = (_Float16)expf(-10.0f * c.x);
            h[1] = (_Float16)expf(-10.0f * c.y);
            h[2] = (_Float16)expf(-10.0f * c.z);
            h[3] = (_Float16)expf(-10.0f * c.w);
            *(half4_t*)&band[rloc][4 * j4] = h;
            s += (double)(float)h[0] + (double)(float)h[1]
               + (double)(float)h[2] + (double)(float)h[3];
        }
        for (int off = 32; off; off >>= 1) s += __shfl_xor(s, off, 64);
        __syncthreads();                      // s16 free (b_sum readers done)
        if (lane == 0) s16[tid >> 6] = s;     // 2 waves per row
        __syncthreads();
        if (tid < RPB) {
            sRowSum[tid]  = s16[2 * tid] + s16[2 * tid + 1];
            sU[tid] = 1.0; sRowPrev[tid] = 1.0; sUp[tid] = 1.0;
            sVown[tid] = 1.0; sColPrev[tid] = 1.0;
            sAn[tid] = (double)a[r0 + tid] / a_sum;
            sBn[tid] = (double)b[r0 + tid] / b_sum;
        }
        __syncthreads();
        if (tid == 0) {
            double bs = 0.0;
            #pragma unroll
            for (int r = 0; r < RPB; ++r) bs += sRowSum[r];
            ws->bandSum[bid] = bs;
        }
    }
    arrive(&ws->cnt0);
    wait_cnt(&ws->cnt0, NBLK);
    const double k0sum = block_reduce((tid < NBLK) ? ws->bandSum[tid] : 0.0, s16);

    double W = D_MASS / k0sum;   // K_t = U[i]*K0[i,j]*V[j]*W
    double Wp = 0.0;
    bool done = false;

    for (int cpt = 0; cpt < NITER && !done; ++cpt) {
        const bool erriter = (cpt % 10) == 0;

        if (cpt > 0) {   // consume previous iteration's dot -> mass scaling
            wait_cnt(&ws->cntV, (unsigned)(NBLK * cpt));
            const double sd = block_reduce((tid < NBLK) ? ws->dotParts[tid] : 0.0, s16);
            W = D_MASS / sd;
        }
        if (erriter) {
            Wp = W;
            if (tid < RPB) sUp[tid] = sU[tid];
        }
        __syncthreads();

        // ---- A1: row sums (band x V) + row scaling ----
        if (cpt == 0) {
            if (tid < RPB) {
                const double Uq = sU[tid] / sRowPrev[tid];
                double r = sAn[tid] / (Uq * W * sRowSum[tid]);
                if (r > 1.0) r = 1.0;
                sU[tid] = Uq * r; sRowPrev[tid] = r;
            }
        } else {
            const float4* v4 = (const float4*)ws->V;
            double s = 0.0;
            #pragma unroll 4
            for (int j4 = cgrp; j4 < N / 4; j4 += 128) {
                half4_t h = *(const half4_t*)&band[rloc][4 * j4];
                float4 vv = v4[j4];
                s += (double)((float)h[0] * vv.x) + (double)((float)h[1] * vv.y)
                   + (double)((float)h[2] * vv.z) + (double)((float)h[3] * vv.w);
            }
            for (int off = 32; off; off >>= 1) s += __shfl_xor(s, off, 64);
            __syncthreads();
            if (lane == 0) s16[tid >> 6] = s;
            __syncthreads();
            if (tid < RPB) {
                const double Uq = sU[tid] / sRowPrev[tid];
                double r = sAn[tid] / (Uq * W * (s16[2 * tid] + s16[2 * tid + 1]));
                if (r > 1.0) r = 1.0;
                sU[tid] = Uq * r; sRowPrev[tid] = r;
            }
        }
        __syncthreads();

        // ---- A2: column partials over band with new U ----
        {
            double ub[RPB];
            #pragma unroll
            for (int r = 0; r < RPB; ++r) ub[r] = sU[r];
            const int j0 = 2 * tid;
            double ax = 0.0, ay = 0.0;
            #pragma unroll
            for (int r = 0; r < RPB; ++r) {
                half2_t hv = *(const half2_t*)&band[r][j0];
                ax += (double)(float)hv[0] * ub[r];
                ay += (double)(float)hv[1] * ub[r];
            }
            float2 o; o.x = (float)ax; o.y = (float)ay;
            *(float2*)(ws->partialT + (size_t)bid * N + j0) = o;
        }
        arrive(&ws->cntP);
        wait_cnt(&ws->cntP, (unsigned)(NBLK * (cpt + 1)));

        // ---- B: own 8 columns -> T_j, col scaling, V, dot partial ----
        {
            const int g = tid >> 3, jj = tid & 7;
            const int j = r0 + jj;
            sred[g][jj] = (double)ws->partialT[(size_t)g * N + j]
                        + (double)ws->partialT[(size_t)(g + 128) * N + j];
            __syncthreads();
            for (int s2 = 64; s2 > 0; s2 >>= 1) {
                if (g < s2) sred[g][jj] += sred[g + s2][jj];
                __syncthreads();
            }
            if (tid < RPB) {
                const double Tj = sred[0][tid];
                const double Vq = sVown[tid] / sColPrev[tid];
                double cf = sBn[tid] / (Vq * W * Tj);
                if (cf > 1.0) cf = 1.0;
                if (erriter) ws->Vp[r0 + tid] = (float)sVown[tid];
                const double Vn = Vq * cf;
                sVown[tid] = Vn; sColPrev[tid] = cf;
                ws->V[r0 + tid] = (float)Vn;
                sdotLoc[tid] = Tj * Vn;
            }
            __syncthreads();
            if (tid == 0) {
                double d = 0.0;
                #pragma unroll
                for (int q = 0; q < RPB; ++q) d += sdotLoc[q];
                ws->dotParts[bid] = d;
            }
        }
        arrive(&ws->cntV);

        // ---- err check fused with speculative output write ----
        if (erriter) {
            wait_cnt(&ws->cntV, (unsigned)(NBLK * (cpt + 1)));
            const double sd = block_reduce((tid < NBLK) ? ws->dotParts[tid] : 0.0, s16);
            const double Wn = D_MASS / sd;
            const int i = r0 + rloc;
            const double upw = sUp[rloc] * Wp;
            const double unw = sU[rloc] * Wn;
            const float4* vp4 = (const float4*)ws->Vp;
            const float4* vn4 = (const float4*)ws->V;
            float4* k4 = (float4*)(K + (size_t)i * N);
            double e2 = 0.0;
            #pragma unroll 4
            for (int j4 = cgrp; j4 < N / 4; j4 += 128) {
                half4_t h = *(const half4_t*)&band[rloc][4 * j4];
                float4 vp = vp4[j4], vn = vn4[j4];
                const double k0x = (double)(float)h[0], k0y = (double)(float)h[1];
                const double k0z = (double)(float)h[2], k0w = (double)(float)h[3];
                float4 kn;
                kn.x = (float)(unw * k0x * (double)vn.x);
                kn.y = (float)(unw * k0y * (double)vn.y);
                kn.z = (float)(unw * k0z * (double)vn.z);
                kn.w = (float)(unw * k0w * (double)vn.w);
                k4[j4] = kn;                  // speculative final output
                double d;
                d = k0x * (upw * (double)vp.x - unw * (double)vn.x); e2 += d * d;
                d = k0y * (upw * (double)vp.y - unw * (double)vn.y); e2 += d * d;
                d = k0z * (upw * (double)vp.z - unw * (double)vn.z); e2 += d * d;
                d = k0w * (upw * (double)vp.w - unw * (double)vn.w); e2 += d * d;
            }
            const double be = block_reduce(e2, s16);
            if (tid == 0) ws->errParts[bid] = be;
            arrive(&ws->cntE);
            wait_cnt(&ws->cntE, (unsigned)(NBLK * (cpt / 10 + 1)));
            const double te = block_reduce((tid < NBLK) ? ws->errParts[tid] : 0.0, s16);
            done = (sqrt(te) <= D_TOL);       // bitwise-identical everywhere
        }
    }

    // ---- only if never converged: final output write ----
    if (!done) {
        wait_cnt(&ws->cntV, (unsigned)(NBLK * NITER));
        const double sd = block_reduce((tid < NBLK) ? ws->dotParts[tid] : 0.0, s16);
        const double Wf = D_MASS / sd;
        const int i = r0 + rloc;
        const double uf = sU[rloc] * Wf;
        const float4* vn4 = (const float4*)ws->V;
        float4* k4 = (float4*)(K + (size_t)i * N);
        #pragma unroll 4
        for (int j4 = cgrp; j4 < N / 4; j4 += 128) {
            half4_t h = *(const half4_t*)&band[rloc][4 * j4];
            float4 vv = vn4[j4];
            float4 o;
            o.x = (float)(uf * (double)(float)h[0] * (double)vv.x);
            o.y = (float)(uf * (double)(float)h[1] * (double)vv.y);
            o.z = (float)(uf * (double)(float)h[2] * (double)vv.z);
            o.w = (float)(uf * (double)(float)h[3] * (double)vv.w);
            k4[j4] = o;
        }
    }
}

extern "C" void kernel_launch(void* const* d_in, const int* in_sizes, int n_in,
                              void* d_out, int out_size, void* d_ws, size_t ws_size,
                              hipStream_t stream) {
    const float* C = (const float*)d_in[0];
    const float* a = (const float*)d_in[1];
    const float* b = (const float*)d_in[2];
    float* K = (float*)d_out;
    Ws*    w = (Ws*)d_ws;
    init_counters<<<1, 64, 0, stream>>>(w);
    void* args[5] = { (void*)&C, (void*)&a, (void*)&b, (void*)&K, (void*)&w };
    (void)hipLaunchCooperativeKernel((const void*)epot_kernel, dim3(NBLK), dim3(NTHR),
                                     args, 0, stream);
}